// Round 4
// baseline (200.478 us; speedup 1.0000x reference)
//
#include <hip/hip_runtime.h>
#include <hip/hip_bf16.h>
#include <math.h>

#define B    4
#define QL   2048
#define KVL  2048
#define CQ   256
#define CKV  256
#define CH   32
#define NH   8
#define DM   256   // NH*CH
#define QB   128   // q rows per fattn block (8 waves x 16)
#define KVB  128   // kv strip per iteration

typedef __attribute__((ext_vector_type(8))) short short8;   // 8 x bf16 (4 VGPR)
typedef __attribute__((ext_vector_type(4))) float f32x4;

static __device__ __forceinline__ short f2bf(float x) {
    __hip_bfloat16 h = __float2bfloat16(x);
    return __builtin_bit_cast(short, h);
}

// ---------------------------------------------------------------------------
// prep: fp32 -> bf16 copy (8 elems/thread)
// ---------------------------------------------------------------------------
__global__ __launch_bounds__(256) void prep_cvt(
    const float* __restrict__ src, short* __restrict__ dst, int n8)
{
    int i = blockIdx.x * 256 + threadIdx.x;
    if (i >= n8) return;
    const float4* s = (const float4*)src + (size_t)i * 2;
    float4 a = s[0], b = s[1];
    short8 o = { f2bf(a.x), f2bf(a.y), f2bf(a.z), f2bf(a.w),
                 f2bf(b.x), f2bf(b.y), f2bf(b.z), f2bf(b.w) };
    *((short8*)dst + i) = o;
}

// ---------------------------------------------------------------------------
// prep: W [K][N] fp32 -> W^T [N][K] bf16, 32x32 LDS tiles
// ---------------------------------------------------------------------------
__global__ __launch_bounds__(256) void prep_wT(
    const float* __restrict__ w, short* __restrict__ wt, int K, int N)
{
    __shared__ float tile[32][33];
    const int bx = blockIdx.x * 32;            // n
    const int by = blockIdx.y * 32;            // k
    const int tx = threadIdx.x & 31, ty = threadIdx.x >> 5;
    #pragma unroll
    for (int i = 0; i < 32; i += 8)
        tile[ty + i][tx] = w[(size_t)(by + ty + i) * N + bx + tx];
    __syncthreads();
    #pragma unroll
    for (int i = 0; i < 32; i += 8)
        wt[(size_t)(bx + ty + i) * K + by + tx] = f2bf(tile[tx][ty + i]);
}

// ---------------------------------------------------------------------------
// bf16 MFMA GEMM (unchanged from R3): A [M][K] bf16, BT [N][K] bf16.
// 64x64 tile, 4 waves (2x2 of 32x32), BK=32.
// ---------------------------------------------------------------------------
__global__ __launch_bounds__(256) void gemm_mfma(
    const short* __restrict__ A, const short* __restrict__ BT,
    const float* __restrict__ bias, float* __restrict__ outf,
    short* __restrict__ outb,
    int M, int N, int K, float alpha, int mode)
{
    __shared__ __align__(16) short As[64][40];
    __shared__ __align__(16) short Bs[64][40];

    const int t   = threadIdx.x;
    const int m0  = blockIdx.y * 64, n0 = blockIdx.x * 64;
    const int lane = t & 63, w = t >> 6;
    const int c16 = lane & 15, g = lane >> 4;
    const int wm  = (w & 1) * 32, wn = (w >> 1) * 32;
    const int lr  = t >> 2, lc = (t & 3) * 8;

    f32x4 acc[2][2] = {};

    for (int k0 = 0; k0 < K; k0 += 32) {
        __syncthreads();
        *(short8*)&As[lr][lc] = *(const short8*)(A  + (size_t)(m0 + lr) * K + k0 + lc);
        *(short8*)&Bs[lr][lc] = *(const short8*)(BT + (size_t)(n0 + lr) * K + k0 + lc);
        __syncthreads();

        short8 af[2], bf[2];
        #pragma unroll
        for (int i = 0; i < 2; i++) {
            af[i] = *(const short8*)&As[wm + i * 16 + c16][g * 8];
            bf[i] = *(const short8*)&Bs[wn + i * 16 + c16][g * 8];
        }
        #pragma unroll
        for (int i = 0; i < 2; i++)
            #pragma unroll
            for (int j = 0; j < 2; j++)
                acc[i][j] = __builtin_amdgcn_mfma_f32_16x16x32_bf16(af[i], bf[j], acc[i][j], 0, 0, 0);
    }

    #pragma unroll
    for (int i = 0; i < 2; i++) {
        #pragma unroll
        for (int j = 0; j < 2; j++) {
            #pragma unroll
            for (int r = 0; r < 4; r++) {
                int m = m0 + wm + i * 16 + g * 4 + r;
                int n = n0 + wn + j * 16 + c16;
                float v = acc[i][j][r] * alpha;
                if (mode == 0) {
                    outf[(size_t)m * N + n] = v + (bias ? bias[n] : 0.0f);
                } else {
                    int bb = m >> 11, l = m & 2047;
                    int hh = n >> 5,  cc = n & 31;
                    if (mode == 1)
                        outb[(((size_t)bb * NH + hh) * QL + l) * CH + cc] = f2bf(v);
                    else
                        outb[(((size_t)bb * NH + hh) * CH + cc) * (size_t)KVL + l] = f2bf(v);
                }
            }
        }
    }
}

// ---------------------------------------------------------------------------
// Flash attention, R4: 8 waves (512 thr), QB=128; static-max softmax (exp2,
// log2e folded into Q scale); double-buffered K/V with register prefetch;
// ONE barrier per strip; setprio around MFMA clusters.
// Fragment maps (m89-derived, self-consistent):
//   A-frag lane: A[m=lane&15][k=(lane>>4)*8+j]
//   B-frag lane: B[k=(lane>>4)*8+j][n=lane&15]
//   D-frag lane reg r: D[row=(lane>>4)*4+r][col=lane&15]
// ---------------------------------------------------------------------------
__global__ __launch_bounds__(512, 4) void fattn(
    const short* __restrict__ qbf, const short* __restrict__ kbf,
    const short* __restrict__ vtb, const float* __restrict__ mask,
    const float* __restrict__ bias, short* __restrict__ aob)
{
    __shared__ __align__(16) short Kl[2][KVB * 32];   // 16 KB, swizzled
    __shared__ __align__(16) short Vl[2][32 * KVB];   // 16 KB, swizzled (V^T)
    __shared__ __align__(16) short Pl[8][16 * KVB];   // 32 KB, per-wave, swizzled

    const int t    = threadIdx.x;
    const int w    = t >> 6;
    const int lane = t & 63;
    const int c16  = lane & 15;
    const int g    = lane >> 4;

    const int q0 = blockIdx.x * QB;
    const int h  = blockIdx.y, b = blockIdx.z;
    const int bh = b * NH + h;

    // Q fragment: row q0 + w*16 + c16 (scale * log2e folded in projection)
    short8 qf = *(const short8*)(qbf + ((size_t)bh * QL + q0 + w * 16 + c16) * CH + g * 8);

    f32x4 o0 = {0.f, 0.f, 0.f, 0.f}, o1 = {0.f, 0.f, 0.f, 0.f};
    float l_r[4] = {0.f, 0.f, 0.f, 0.f};

    const float* bias_base = bias + ((size_t)h * QL + q0 + w * 16) * KVL;
    const float* mask_base = mask + (size_t)b * KVL;

    // per-thread staging addresses (K: [128 kv][32 ch], V^T: [32 ch][128 kv])
    const short* ksrc = kbf + (size_t)bh * KVL * CH + (t >> 2) * CH + (t & 3) * 8;
    const short* vsrc = vtb + (size_t)bh * CH * KVL + (t >> 4) * KVL + (t & 15) * 8;
    const int krow = t >> 2,  kch = t & 3;
    const int kbyte = (krow * 64 + kch * 16) ^ ((krow & 7) << 4);
    const int vrow = t >> 4,  vch = t & 15;
    const int vbyte = (vrow * 256 + vch * 16) ^ ((vrow & 7) << 4);

    short8 kreg = *(const short8*)ksrc;     // prefetch strip 0
    short8 vreg = *(const short8*)vsrc;

    short* pw = &Pl[w][0];
    const f32x4 zero4 = {0.f, 0.f, 0.f, 0.f};
    constexpr float L2E  = 1.4426950408889634f;
    constexpr float MBIG = 1e9f * L2E;                 // mask slope * log2e
    constexpr float MOFF = -(1e9f * L2E) - 40.0f * L2E; // -MBIG - C  (C = static max * log2e)

    #pragma unroll 1
    for (int it = 0; it < KVL / KVB; ++it) {
        const int kv0 = it * KVB;
        char* klb = (char*)Kl[it & 1];
        char* vlb = (char*)Vl[it & 1];

        // ---- stage prefetched registers -> LDS, one barrier ----
        *(short8*)(klb + kbyte) = kreg;
        *(short8*)(vlb + vbyte) = vreg;
        __syncthreads();

        // ---- issue next strip's global loads (overlap with compute) ----
        if (it + 1 < KVL / KVB) {
            kreg = *(const short8*)(ksrc + (size_t)(it + 1) * KVB * CH);
            vreg = *(const short8*)(vsrc + (it + 1) * KVB);
        }

        // ---- mask terms: mt = (mk-1)*1e9*log2e - C ----
        float mt[8];
        #pragma unroll
        for (int tt = 0; tt < 8; ++tt)
            mt[tt] = fmaf(mask_base[kv0 + tt * 16 + c16], MBIG, MOFF);

        // ---- QK^T: 8 subtiles (S' in log2e units) ----
        f32x4 s[8];
        __builtin_amdgcn_s_setprio(1);
        #pragma unroll
        for (int tt = 0; tt < 8; ++tt) {
            int row  = tt * 16 + c16;
            int byte = (row * 64 + g * 16) ^ ((row & 7) << 4);
            short8 kf = *(const short8*)(klb + byte);
            s[tt] = __builtin_amdgcn_mfma_f32_16x16x32_bf16(qf, kf, zero4, 0, 0, 0);
        }
        __builtin_amdgcn_s_setprio(0);

        // ---- p = exp2(s + bias*log2e + mt); accumulate l; write P (bf16) ----
        #pragma unroll
        for (int tt = 0; tt < 8; ++tt) {
            #pragma unroll
            for (int r = 0; r < 4; ++r) {
                float bi = bias_base[(size_t)(4 * g + r) * KVL + kv0 + tt * 16 + c16];
                float p  = __builtin_amdgcn_exp2f(fmaf(bi, L2E, s[tt][r] + mt[tt]));
                l_r[r] += p;
                int q    = 4 * g + r;
                int byte = (q * 256 + (tt * 16 + c16) * 2) ^ ((q & 7) << 4);
                *(short*)((char*)pw + byte) = f2bf(p);
            }
        }

        // same-wave cross-lane LDS write->read: make ordering explicit
        asm volatile("s_waitcnt lgkmcnt(0)" ::: "memory");

        // ---- PV: O[16q][32c] += P[16][128] @ V[128][32] ----
        __builtin_amdgcn_s_setprio(1);
        #pragma unroll
        for (int kk = 0; kk < 4; ++kk) {
            int cb = (kk * 32 + g * 8) * 2;
            int pb  = (c16 * 256 + cb) ^ ((c16 & 7) << 4);
            short8 pf  = *(const short8*)((const char*)pw + pb);
            short8 vf0 = *(const short8*)(vlb + ((c16 * 256 + cb) ^ ((c16 & 7) << 4)));
            short8 vf1 = *(const short8*)(vlb + (((16 + c16) * 256 + cb) ^ ((c16 & 7) << 4)));
            o0 = __builtin_amdgcn_mfma_f32_16x16x32_bf16(pf, vf0, o0, 0, 0, 0);
            o1 = __builtin_amdgcn_mfma_f32_16x16x32_bf16(pf, vf1, o1, 0, 0, 0);
        }
        __builtin_amdgcn_s_setprio(0);
    }

    // ---- finalize: reduce row-sums across 16-lane group, write O ----
    #pragma unroll
    for (int r = 0; r < 4; r++) {
        #pragma unroll
        for (int off = 1; off < 16; off <<= 1)
            l_r[r] += __shfl_xor(l_r[r], off);
    }
    short* aop = aob + ((size_t)b * QL + q0 + w * 16) * DM + h * CH;
    #pragma unroll
    for (int r = 0; r < 4; r++) {
        float inv = 1.0f / l_r[r];
        int q = 4 * g + r;
        aop[(size_t)q * DM + c16]      = f2bf(o0[r] * inv);
        aop[(size_t)q * DM + 16 + c16] = f2bf(o1[r] * inv);
    }
}

// ---------------------------------------------------------------------------
extern "C" void kernel_launch(void* const* d_in, const int* in_sizes, int n_in,
                              void* d_out, int out_size, void* d_ws, size_t ws_size,
                              hipStream_t stream)
{
    const float* input_q  = (const float*)d_in[0];
    const float* input_kv = (const float*)d_in[1];
    const float* mask     = (const float*)d_in[2];
    const float* bias     = (const float*)d_in[3];
    const float* w_q      = (const float*)d_in[4];
    const float* w_k      = (const float*)d_in[5];
    const float* w_v      = (const float*)d_in[6];
    const float* w_o      = (const float*)d_in[7];
    const float* b_o      = (const float*)d_in[8];
    float* out = (float*)d_out;

    const size_t TOK  = (size_t)B * QL;            // 8192
    const size_t HEAD = (size_t)B * NH * QL * CH;  // 2,097,152 elems

    short* qbf = (short*)d_ws;          // bf16 Q  head-split       4 MB
    short* kbf = qbf + HEAD;            // bf16 K  head-split       4 MB
    short* vtb = kbf + HEAD;            // bf16 V^T head-split      4 MB
    short* aob = vtb + HEAD;            // bf16 attn out [tok][dm]  4 MB
    short* qx  = aob + HEAD;            // bf16 input_q             4 MB
    short* kvx = qx  + HEAD;            // bf16 input_kv            4 MB
    short* wqT = kvx + HEAD;            // bf16 w_q^T  [N][K]       128 KB
    short* wkT = wqT + CQ * DM;
    short* wvT = wkT + CKV * DM;
    short* woT = wvT + CKV * DM;

    dim3 blk(256);
    // 1/sqrt(32) * log2(e): static-max softmax works in exp2 units
    const float qscale = 0.17677669529663687f * 1.4426950408889634f;

    prep_cvt<<<dim3((TOK * CQ / 8 + 255) / 256), blk, 0, stream>>>(input_q,  qx,  (int)(TOK * CQ / 8));
    prep_cvt<<<dim3((TOK * CKV / 8 + 255) / 256), blk, 0, stream>>>(input_kv, kvx, (int)(TOK * CKV / 8));
    prep_wT<<<dim3(DM / 32, CQ / 32),  blk, 0, stream>>>(w_q, wqT, CQ,  DM);
    prep_wT<<<dim3(DM / 32, CKV / 32), blk, 0, stream>>>(w_k, wkT, CKV, DM);
    prep_wT<<<dim3(DM / 32, CKV / 32), blk, 0, stream>>>(w_v, wvT, CKV, DM);
    prep_wT<<<dim3(CQ / 32, DM / 32),  blk, 0, stream>>>(w_o, woT, DM,  CQ);

    dim3 pgrid(DM / 64, TOK / 64);                 // (4, 128)
    gemm_mfma<<<pgrid, blk, 0, stream>>>(qx,  wqT, nullptr, nullptr, qbf,
                                         (int)TOK, DM, CQ,  qscale, 1);
    gemm_mfma<<<pgrid, blk, 0, stream>>>(kvx, wkT, nullptr, nullptr, kbf,
                                         (int)TOK, DM, CKV, 1.0f, 1);
    gemm_mfma<<<pgrid, blk, 0, stream>>>(kvx, wvT, nullptr, nullptr, vtb,
                                         (int)TOK, DM, CKV, 1.0f, 2);

    fattn<<<dim3(QL / QB, NH, B), dim3(512), 0, stream>>>(qbf, kbf, vtb, mask, bias, aob);

    gemm_mfma<<<dim3(CQ / 64, TOK / 64), blk, 0, stream>>>(aob, woT, b_o, out, nullptr,
                                         (int)TOK, CQ, DM, 1.0f, 0);
}

// Round 5
// 118.312 us; speedup vs baseline: 1.6945x; 1.6945x over previous
//
#include <hip/hip_runtime.h>
#include <hip/hip_bf16.h>
#include <math.h>

#define B    4
#define QL   2048
#define KVL  2048
#define CQ   256
#define CKV  256
#define CH   32
#define NH   8
#define DM   256   // NH*CH
#define QB   128   // q rows per fattn block (8 waves x 16)
#define KVB  128   // kv strip per iteration

typedef __attribute__((ext_vector_type(8))) short short8;   // 8 x bf16 (4 VGPR)
typedef __attribute__((ext_vector_type(4))) float f32x4;

static __device__ __forceinline__ short f2bf(float x) {
    __hip_bfloat16 h = __float2bfloat16(x);
    return __builtin_bit_cast(short, h);
}

// ---------------------------------------------------------------------------
// prep: fp32 -> bf16 copy (8 elems/thread)
// ---------------------------------------------------------------------------
__global__ __launch_bounds__(256) void prep_cvt(
    const float* __restrict__ src, short* __restrict__ dst, int n8)
{
    int i = blockIdx.x * 256 + threadIdx.x;
    if (i >= n8) return;
    const float4* s = (const float4*)src + (size_t)i * 2;
    float4 a = s[0], b = s[1];
    short8 o = { f2bf(a.x), f2bf(a.y), f2bf(a.z), f2bf(a.w),
                 f2bf(b.x), f2bf(b.y), f2bf(b.z), f2bf(b.w) };
    *((short8*)dst + i) = o;
}

// ---------------------------------------------------------------------------
// prep: W [K][N] fp32 -> W^T [N][K] bf16, 32x32 LDS tiles
// ---------------------------------------------------------------------------
__global__ __launch_bounds__(256) void prep_wT(
    const float* __restrict__ w, short* __restrict__ wt, int K, int N)
{
    __shared__ float tile[32][33];
    const int bx = blockIdx.x * 32;            // n
    const int by = blockIdx.y * 32;            // k
    const int tx = threadIdx.x & 31, ty = threadIdx.x >> 5;
    #pragma unroll
    for (int i = 0; i < 32; i += 8)
        tile[ty + i][tx] = w[(size_t)(by + ty + i) * N + bx + tx];
    __syncthreads();
    #pragma unroll
    for (int i = 0; i < 32; i += 8)
        wt[(size_t)(bx + ty + i) * K + by + tx] = f2bf(tile[tx][ty + i]);
}

// ---------------------------------------------------------------------------
// bf16 MFMA GEMM (unchanged): A [M][K] bf16, BT [N][K] bf16.
// 64x64 tile, 4 waves (2x2 of 32x32), BK=32.
// ---------------------------------------------------------------------------
__global__ __launch_bounds__(256) void gemm_mfma(
    const short* __restrict__ A, const short* __restrict__ BT,
    const float* __restrict__ bias, float* __restrict__ outf,
    short* __restrict__ outb,
    int M, int N, int K, float alpha, int mode)
{
    __shared__ __align__(16) short As[64][40];
    __shared__ __align__(16) short Bs[64][40];

    const int t   = threadIdx.x;
    const int m0  = blockIdx.y * 64, n0 = blockIdx.x * 64;
    const int lane = t & 63, w = t >> 6;
    const int c16 = lane & 15, g = lane >> 4;
    const int wm  = (w & 1) * 32, wn = (w >> 1) * 32;
    const int lr  = t >> 2, lc = (t & 3) * 8;

    f32x4 acc[2][2] = {};

    for (int k0 = 0; k0 < K; k0 += 32) {
        __syncthreads();
        *(short8*)&As[lr][lc] = *(const short8*)(A  + (size_t)(m0 + lr) * K + k0 + lc);
        *(short8*)&Bs[lr][lc] = *(const short8*)(BT + (size_t)(n0 + lr) * K + k0 + lc);
        __syncthreads();

        short8 af[2], bf[2];
        #pragma unroll
        for (int i = 0; i < 2; i++) {
            af[i] = *(const short8*)&As[wm + i * 16 + c16][g * 8];
            bf[i] = *(const short8*)&Bs[wn + i * 16 + c16][g * 8];
        }
        #pragma unroll
        for (int i = 0; i < 2; i++)
            #pragma unroll
            for (int j = 0; j < 2; j++)
                acc[i][j] = __builtin_amdgcn_mfma_f32_16x16x32_bf16(af[i], bf[j], acc[i][j], 0, 0, 0);
    }

    #pragma unroll
    for (int i = 0; i < 2; i++) {
        #pragma unroll
        for (int j = 0; j < 2; j++) {
            #pragma unroll
            for (int r = 0; r < 4; r++) {
                int m = m0 + wm + i * 16 + g * 4 + r;
                int n = n0 + wn + j * 16 + c16;
                float v = acc[i][j][r] * alpha;
                if (mode == 0) {
                    outf[(size_t)m * N + n] = v + (bias ? bias[n] : 0.0f);
                } else {
                    int bb = m >> 11, l = m & 2047;
                    int hh = n >> 5,  cc = n & 31;
                    if (mode == 1)
                        outb[(((size_t)bb * NH + hh) * QL + l) * CH + cc] = f2bf(v);
                    else
                        outb[(((size_t)bb * NH + hh) * CH + cc) * (size_t)KVL + l] = f2bf(v);
                }
            }
        }
    }
}

// ---------------------------------------------------------------------------
// Flash attention, R5: 8 waves (512 thr), QB=128; static-max softmax (exp2,
// log2e folded into Q scale); double-buffered K/V w/ register prefetch; ONE
// barrier per strip; bias+mask PREFETCHED TO REGISTERS before the barrier
// (R4 regression fix #2); no min-waves VGPR cap (R4 regression fix #1).
// Fragment maps (m89-derived, self-consistent):
//   A-frag lane: A[m=lane&15][k=(lane>>4)*8+j]
//   B-frag lane: B[k=(lane>>4)*8+j][n=lane&15]
//   D-frag lane reg r: D[row=(lane>>4)*4+r][col=lane&15]
// ---------------------------------------------------------------------------
__global__ __launch_bounds__(512) void fattn(
    const short* __restrict__ qbf, const short* __restrict__ kbf,
    const short* __restrict__ vtb, const float* __restrict__ mask,
    const float* __restrict__ bias, short* __restrict__ aob)
{
    __shared__ __align__(16) short Kl[2][KVB * 32];   // 16 KB, swizzled
    __shared__ __align__(16) short Vl[2][32 * KVB];   // 16 KB, swizzled (V^T)
    __shared__ __align__(16) short Pl[8][16 * KVB];   // 32 KB, per-wave, swizzled

    const int t    = threadIdx.x;
    const int w    = t >> 6;
    const int lane = t & 63;
    const int c16  = lane & 15;
    const int g    = lane >> 4;

    const int q0 = blockIdx.x * QB;
    const int h  = blockIdx.y, b = blockIdx.z;
    const int bh = b * NH + h;

    // Q fragment: row q0 + w*16 + c16 (scale * log2e folded in projection)
    short8 qf = *(const short8*)(qbf + ((size_t)bh * QL + q0 + w * 16 + c16) * CH + g * 8);

    f32x4 o0 = {0.f, 0.f, 0.f, 0.f}, o1 = {0.f, 0.f, 0.f, 0.f};
    float l_r[4] = {0.f, 0.f, 0.f, 0.f};

    const float* bias_base = bias + ((size_t)h * QL + q0 + w * 16) * KVL;
    const float* mask_base = mask + (size_t)b * KVL;

    // per-thread staging addresses (K: [128 kv][32 ch], V^T: [32 ch][128 kv])
    const short* ksrc = kbf + (size_t)bh * KVL * CH + (t >> 2) * CH + (t & 3) * 8;
    const short* vsrc = vtb + (size_t)bh * CH * KVL + (t >> 4) * KVL + (t & 15) * 8;
    const int krow = t >> 2,  kch = t & 3;
    const int kbyte = (krow * 64 + kch * 16) ^ ((krow & 7) << 4);
    const int vrow = t >> 4,  vch = t & 15;
    const int vbyte = (vrow * 256 + vch * 16) ^ ((vrow & 7) << 4);

    short8 kreg = *(const short8*)ksrc;     // prefetch strip 0
    short8 vreg = *(const short8*)vsrc;

    short* pw = &Pl[w][0];
    const f32x4 zero4 = {0.f, 0.f, 0.f, 0.f};
    constexpr float L2E  = 1.4426950408889634f;
    constexpr float MBIG = 1e9f * L2E;                  // mask slope * log2e
    constexpr float MOFF = -(1e9f * L2E) - 40.0f * L2E; // -MBIG - C (C = static max, exp2 units)

    #pragma unroll 1
    for (int it = 0; it < KVL / KVB; ++it) {
        const int kv0 = it * KVB;
        char* klb = (char*)Kl[it & 1];
        char* vlb = (char*)Vl[it & 1];

        // ---- prefetch bias + mask into REGISTERS (33 independent loads,
        //      issued before the barrier; latency hides under stage+QK^T) ----
        float bi[8][4], mt[8];
        #pragma unroll
        for (int tt = 0; tt < 8; ++tt) {
            mt[tt] = fmaf(mask_base[kv0 + tt * 16 + c16], MBIG, MOFF);
            #pragma unroll
            for (int r = 0; r < 4; ++r)
                bi[tt][r] = bias_base[(size_t)(4 * g + r) * KVL + kv0 + tt * 16 + c16];
        }

        // ---- stage prefetched K/V registers -> LDS, one barrier ----
        *(short8*)(klb + kbyte) = kreg;
        *(short8*)(vlb + vbyte) = vreg;
        __syncthreads();

        // ---- issue next strip's global loads (overlap with compute) ----
        if (it + 1 < KVL / KVB) {
            kreg = *(const short8*)(ksrc + (size_t)(it + 1) * KVB * CH);
            vreg = *(const short8*)(vsrc + (it + 1) * KVB);
        }

        // ---- QK^T: 8 subtiles (S' in exp2 units) ----
        f32x4 s[8];
        __builtin_amdgcn_s_setprio(1);
        #pragma unroll
        for (int tt = 0; tt < 8; ++tt) {
            int row  = tt * 16 + c16;
            int byte = (row * 64 + g * 16) ^ ((row & 7) << 4);
            short8 kf = *(const short8*)(klb + byte);
            s[tt] = __builtin_amdgcn_mfma_f32_16x16x32_bf16(qf, kf, zero4, 0, 0, 0);
        }
        __builtin_amdgcn_s_setprio(0);

        // ---- p = exp2(s + bias*log2e + mt); accumulate l; write P (bf16) ----
        #pragma unroll
        for (int tt = 0; tt < 8; ++tt) {
            #pragma unroll
            for (int r = 0; r < 4; ++r) {
                float p = __builtin_amdgcn_exp2f(fmaf(bi[tt][r], L2E, s[tt][r] + mt[tt]));
                l_r[r] += p;
                int q    = 4 * g + r;
                int byte = (q * 256 + (tt * 16 + c16) * 2) ^ ((q & 7) << 4);
                *(short*)((char*)pw + byte) = f2bf(p);
            }
        }

        // same-wave cross-lane LDS write->read: explicit ordering (rule #18)
        asm volatile("s_waitcnt lgkmcnt(0)" ::: "memory");
        __builtin_amdgcn_sched_barrier(0);

        // ---- PV: O[16q][32c] += P[16][128] @ V[128][32] ----
        __builtin_amdgcn_s_setprio(1);
        #pragma unroll
        for (int kk = 0; kk < 4; ++kk) {
            int cb = (kk * 32 + g * 8) * 2;
            int pb  = (c16 * 256 + cb) ^ ((c16 & 7) << 4);
            short8 pf  = *(const short8*)((const char*)pw + pb);
            short8 vf0 = *(const short8*)(vlb + ((c16 * 256 + cb) ^ ((c16 & 7) << 4)));
            short8 vf1 = *(const short8*)(vlb + (((16 + c16) * 256 + cb) ^ ((c16 & 7) << 4)));
            o0 = __builtin_amdgcn_mfma_f32_16x16x32_bf16(pf, vf0, o0, 0, 0, 0);
            o1 = __builtin_amdgcn_mfma_f32_16x16x32_bf16(pf, vf1, o1, 0, 0, 0);
        }
        __builtin_amdgcn_s_setprio(0);
    }

    // ---- finalize: reduce row-sums across 16-lane group, write O ----
    #pragma unroll
    for (int r = 0; r < 4; r++) {
        #pragma unroll
        for (int off = 1; off < 16; off <<= 1)
            l_r[r] += __shfl_xor(l_r[r], off);
    }
    short* aop = aob + ((size_t)b * QL + q0 + w * 16) * DM + h * CH;
    #pragma unroll
    for (int r = 0; r < 4; r++) {
        float inv = 1.0f / l_r[r];
        int q = 4 * g + r;
        aop[(size_t)q * DM + c16]      = f2bf(o0[r] * inv);
        aop[(size_t)q * DM + 16 + c16] = f2bf(o1[r] * inv);
    }
}

// ---------------------------------------------------------------------------
extern "C" void kernel_launch(void* const* d_in, const int* in_sizes, int n_in,
                              void* d_out, int out_size, void* d_ws, size_t ws_size,
                              hipStream_t stream)
{
    const float* input_q  = (const float*)d_in[0];
    const float* input_kv = (const float*)d_in[1];
    const float* mask     = (const float*)d_in[2];
    const float* bias     = (const float*)d_in[3];
    const float* w_q      = (const float*)d_in[4];
    const float* w_k      = (const float*)d_in[5];
    const float* w_v      = (const float*)d_in[6];
    const float* w_o      = (const float*)d_in[7];
    const float* b_o      = (const float*)d_in[8];
    float* out = (float*)d_out;

    const size_t TOK  = (size_t)B * QL;            // 8192
    const size_t HEAD = (size_t)B * NH * QL * CH;  // 2,097,152 elems

    short* qbf = (short*)d_ws;          // bf16 Q  head-split       4 MB
    short* kbf = qbf + HEAD;            // bf16 K  head-split       4 MB
    short* vtb = kbf + HEAD;            // bf16 V^T head-split      4 MB
    short* aob = vtb + HEAD;            // bf16 attn out [tok][dm]  4 MB
    short* qx  = aob + HEAD;            // bf16 input_q             4 MB
    short* kvx = qx  + HEAD;            // bf16 input_kv            4 MB
    short* wqT = kvx + HEAD;            // bf16 w_q^T  [N][K]       128 KB
    short* wkT = wqT + CQ * DM;
    short* wvT = wkT + CKV * DM;
    short* woT = wvT + CKV * DM;

    dim3 blk(256);
    // 1/sqrt(32) * log2(e): static-max softmax works in exp2 units
    const float qscale = 0.17677669529663687f * 1.4426950408889634f;

    prep_cvt<<<dim3((TOK * CQ / 8 + 255) / 256), blk, 0, stream>>>(input_q,  qx,  (int)(TOK * CQ / 8));
    prep_cvt<<<dim3((TOK * CKV / 8 + 255) / 256), blk, 0, stream>>>(input_kv, kvx, (int)(TOK * CKV / 8));
    prep_wT<<<dim3(DM / 32, CQ / 32),  blk, 0, stream>>>(w_q, wqT, CQ,  DM);
    prep_wT<<<dim3(DM / 32, CKV / 32), blk, 0, stream>>>(w_k, wkT, CKV, DM);
    prep_wT<<<dim3(DM / 32, CKV / 32), blk, 0, stream>>>(w_v, wvT, CKV, DM);
    prep_wT<<<dim3(CQ / 32, DM / 32),  blk, 0, stream>>>(w_o, woT, DM,  CQ);

    dim3 pgrid(DM / 64, TOK / 64);                 // (4, 128)
    gemm_mfma<<<pgrid, blk, 0, stream>>>(qx,  wqT, nullptr, nullptr, qbf,
                                         (int)TOK, DM, CQ,  qscale, 1);
    gemm_mfma<<<pgrid, blk, 0, stream>>>(kvx, wkT, nullptr, nullptr, kbf,
                                         (int)TOK, DM, CKV, 1.0f, 1);
    gemm_mfma<<<pgrid, blk, 0, stream>>>(kvx, wvT, nullptr, nullptr, vtb,
                                         (int)TOK, DM, CKV, 1.0f, 2);

    fattn<<<dim3(QL / QB, NH, B), dim3(512), 0, stream>>>(qbf, kbf, vtb, mask, bias, aob);

    gemm_mfma<<<dim3(CQ / 64, TOK / 64), blk, 0, stream>>>(aob, woT, b_o, out, nullptr,
                                         (int)TOK, CQ, DM, 1.0f, 0);
}